// Round 6
// baseline (130.767 us; speedup 1.0000x reference)
//
#include <hip/hip_runtime.h>

// Problem: BS=64, N=1024, XC=1024, K=256, YS=768
//   y_k[b,k]   = sum_s y[b,s] * W_y[k,s]
//   z[b,n,k]   = tanh( sum_c x[b,n,c]*W_ch[k,c] + b_ch[k] + y_k[b,k] )
//   out[b*n,k] = softmax_k(z)
// bf16 MFMA GEMM (f32 acc) fused with tanh+softmax epilogue.
// R6: A staged HBM->LDS via global_load_lds in f32 (no VGPR round-trip),
//     triple-buffered; counted vmcnt(4) barriers keep ~40KB/block of HBM
//     loads in flight through every compute (fix the ~50% duty cycle).
//     bf16 cvt moved to fragment read (v_cvt_pk_bf16_f32, same RNE).

#define XC    1024
#define KOUT  256
#define NT    16        // K-steps: 1024 / 64
#define ABSZ  16384     // one f32 A tile: 64 rows x 64 cols x 4B
#define LDSZ  49152     // 3 x ABSZ

typedef float        f32x4_t  __attribute__((ext_vector_type(4)));
typedef unsigned int u32x4_t  __attribute__((ext_vector_type(4)));
typedef unsigned int u32x2_t  __attribute__((ext_vector_type(2)));
typedef __bf16       bf16x8_t __attribute__((ext_vector_type(8)));

__device__ __forceinline__ unsigned short f2bf(float f) {
  unsigned int u = __float_as_uint(f);
  u += 0x7fffu + ((u >> 16) & 1u);        // RNE
  return (unsigned short)(u >> 16);
}

__device__ __forceinline__ float fast_tanh(float v) {
  float e = __expf(2.0f * v);
  return 1.0f - 2.0f / (e + 1.0f);
}

__device__ __forceinline__ void async_copy16(const void* lds, const void* g) {
  // LDS dest: wave-uniform base, HW adds lane*16. Global src is per-lane.
  __builtin_amdgcn_global_load_lds(
      (const __attribute__((address_space(1))) void*)g,
      (__attribute__((address_space(3))) void*)lds, 16, 0, 0);
}

// counted-vmcnt barrier pieces (rule #18: sched_barrier after asm waits)
#define PIPE_WAIT(N) asm volatile("s_waitcnt vmcnt(" #N ")" ::: "memory")

// ---- prep kernel: blocks 0..255 convert W_ch -> fragment-ordered bf16;
//      blocks 256..319 compute bias[b][k] = y[b]·W_y[k] + b_ch[k] (f32).
__global__ void prep_kernel(const float* __restrict__ Wch,
                            const float* __restrict__ y,
                            const float* __restrict__ Wy,
                            const float* __restrict__ bch,
                            unsigned short* __restrict__ wbf,
                            float* __restrict__ biasws) {
  if (blockIdx.x < 256) {
    const int k = blockIdx.x;            // 0..255
    const int u = threadIdx.x;           // 0..255 ; c0 = 4u
    f32x4_t v = ((const f32x4_t*)(Wch + k * XC))[u];
    const int c0   = u << 2;
    const int t    = c0 >> 6;            // K-step tile
    const int ch   = (c0 & 63) >> 3;     // 16B chunk within tile
    const int kk   = ch >> 2;
    const int lg   = ch & 3;
    const int half = (c0 >> 2) & 1;      // which 8B of the 16B chunk
    const int wv   = k >> 6;
    const int ni   = (k >> 4) & 3;
    const int lr   = k & 15;
    const int lane = (lg << 4) | lr;
    unsigned int lo = (unsigned int)f2bf(v.x) | ((unsigned int)f2bf(v.y) << 16);
    unsigned int hi = (unsigned int)f2bf(v.z) | ((unsigned int)f2bf(v.w) << 16);
    char* p = (char*)wbf +
              ((size_t)((((t << 2) + wv) * 2 + kk) * 4 + ni) << 10) +
              (lane << 4) + (half << 3);
    *(u32x2_t*)p = (u32x2_t){lo, hi};
  } else {
    __shared__ __align__(16) float ys[768];
    const int b = blockIdx.x - 256;      // 0..63
    const int k = threadIdx.x;           // 0..255
    for (int i = k; i < 768; i += 256) ys[i] = y[b * 768 + i];
    __syncthreads();
    const f32x4_t* w4 = (const f32x4_t*)(Wy + k * 768);
    const f32x4_t* y4 = (const f32x4_t*)ys;
    float s = 0.f;
#pragma unroll 8
    for (int i = 0; i < 192; ++i) {
      f32x4_t w = w4[i], a = y4[i];
      s = fmaf(w.x, a.x, s); s = fmaf(w.y, a.y, s);
      s = fmaf(w.z, a.z, s); s = fmaf(w.w, a.w, s);
    }
    biasws[b * 256 + k] = s + bch[k];
  }
}

// ---- main fused kernel: 64 rows/block x 256 cols, 4 waves x 64 cols; BK=64.
// A: f32 DMA into 3-buffered LDS with 32B-chunk XOR swizzle pre-applied on
//    the GLOBAL source (rule #21); read side applies the same XOR.
// B: fragment-ordered bf16 global loads to double-buffered registers.
__global__ __launch_bounds__(256, 3) void fused_kernel(
    const float* __restrict__ x, const unsigned short* __restrict__ wbf,
    const float* __restrict__ bias, float* __restrict__ out) {
  __shared__ __align__(16) unsigned char smem[LDSZ];
  const int tid = threadIdx.x;
  const int l   = tid & 63;
  const int w   = tid >> 6;            // wave 0..3 -> output cols [64w,64w+64)
  const int lr  = l & 15;
  const int lg  = l >> 4;
  const int m0  = blockIdx.x << 6;     // first of 64 rows
  const int bidx = m0 >> 10;           // batch index

  f32x4_t acc[4][4];
#pragma unroll
  for (int i = 0; i < 4; ++i)
#pragma unroll
    for (int j = 0; j < 4; ++j) acc[i][j] = (f32x4_t){0.f, 0.f, 0.f, 0.f};

  const char* xbase = (const char*)x + ((size_t)m0 << 12);
  const char* wsrc  = (const char*)wbf + (w << 13) + (l << 4);
  bf16x8_t bfrA[8], bfrB[8];           // [kk*4+nj], double-buffered

  // DMA A(tt) -> buf: lane covers LDS bytes o = w*4096 + i*1024 + l*16.
  // Logical: row = o>>8, c32 = (o>>5)&7, half = (o>>4)&1.
  // Source pre-swizzled: global chunk = c32 ^ (row&7)  (read applies same XOR)
#define DMA_A(tt, buf) do {                                                  \
    _Pragma("unroll")                                                        \
    for (int i = 0; i < 4; ++i) {                                            \
      const int row = (w << 4) + (i << 2) + (l >> 4);                        \
      const int sw  = ((l >> 1) & 7) ^ (row & 7);                            \
      const char* g = xbase + ((size_t)row << 12) + ((tt) << 8) +            \
                      (sw << 5) + ((l & 1) << 4);                            \
      async_copy16(smem + (buf) * ABSZ + (w << 12) + (i << 10), g);          \
    }                                                                        \
  } while (0)

#define LOADB(dst, tt) do {                                                  \
    const char* g = wsrc + (size_t)(tt) * 32768;                             \
    _Pragma("unroll")                                                        \
    for (int f = 0; f < 8; ++f)                                              \
      dst[f] = __builtin_bit_cast(bf16x8_t, *(const u32x4_t*)(g + (f << 10)));\
  } while (0)

#define COMPUTE(bufc, bsrc) do {                                             \
    const f32x4_t* aB = (const f32x4_t*)(smem + (bufc) * ABSZ);              \
    _Pragma("unroll")                                                        \
    for (int kk = 0; kk < 2; ++kk) {                                         \
      bf16x8_t afr[4];                                                       \
      _Pragma("unroll")                                                      \
      for (int mi = 0; mi < 4; ++mi) {                                       \
        const int row = (mi << 4) + lr;                                      \
        const int sw  = (((kk << 2) | lg) ^ (row & 7));                      \
        f32x4_t lo = aB[(row << 4) + (sw << 1)];                             \
        f32x4_t hi = aB[(row << 4) + (sw << 1) + 1];                         \
        bf16x8_t t_;                                                         \
        t_[0] = (__bf16)lo.x; t_[1] = (__bf16)lo.y;                          \
        t_[2] = (__bf16)lo.z; t_[3] = (__bf16)lo.w;                          \
        t_[4] = (__bf16)hi.x; t_[5] = (__bf16)hi.y;                          \
        t_[6] = (__bf16)hi.z; t_[7] = (__bf16)hi.w;                          \
        afr[mi] = t_;                                                        \
      }                                                                      \
      _Pragma("unroll")                                                      \
      for (int mi = 0; mi < 4; ++mi)                                         \
        _Pragma("unroll")                                                    \
        for (int nj = 0; nj < 4; ++nj)                                       \
          acc[mi][nj] = __builtin_amdgcn_mfma_f32_16x16x32_bf16(             \
              afr[mi], bsrc[(kk << 2) | nj], acc[mi][nj], 0, 0, 0);          \
    }                                                                        \
  } while (0)

  // prologue: order matters for in-order vmcnt counting: A(0), B(0), A(1)
  DMA_A(0, 0);
  LOADB(bfrA, 0);
  DMA_A(1, 1);

#pragma unroll
  for (int s = 0; s < NT; ++s) {
    // WAIT(s): newest 4 in flight = A(s+1); drains A(s), B(s) arrivals.
    if (s < NT - 1) { PIPE_WAIT(4); } else { PIPE_WAIT(0); }
    __builtin_amdgcn_sched_barrier(0);
    __builtin_amdgcn_s_barrier();
    __builtin_amdgcn_sched_barrier(0);
    // issue region: B(s+1) first, then DMA A(s+2) (keeps newest-4 = A)
    if (s + 1 < NT) {
      if (s & 1) LOADB(bfrA, s + 1); else LOADB(bfrB, s + 1);
    }
    if (s + 2 < NT) DMA_A(s + 2, (s + 2) % 3);
    if (s & 1) COMPUTE(s % 3, bfrB); else COMPUTE(s % 3, bfrA);
  }
  __syncthreads();             // all compute done before scratch aliases buf0

#undef DMA_A
#undef LOADB
#undef COMPUTE

  // ---- epilogue: tanh, row-softmax over 256 cols, store
  float* wred    = (float*)smem;           // [4 waves][64 rows]
  float* rowstat = (float*)(smem + 1024);  // [64 rows]

  float brow[4];
#pragma unroll
  for (int ni = 0; ni < 4; ++ni)
    brow[ni] = bias[(bidx << 8) + (w << 6) + (ni << 4) + lr];

#pragma unroll
  for (int mi = 0; mi < 4; ++mi)
#pragma unroll
    for (int ni = 0; ni < 4; ++ni)
#pragma unroll
      for (int r = 0; r < 4; ++r)
        acc[mi][ni][r] = fast_tanh(acc[mi][ni][r] + brow[ni]);

  // per-row max: 4 local cols, then butterfly over the 16-lane col group
#pragma unroll
  for (int mi = 0; mi < 4; ++mi)
#pragma unroll
    for (int r = 0; r < 4; ++r) {
      float m = fmaxf(fmaxf(acc[mi][0][r], acc[mi][1][r]),
                      fmaxf(acc[mi][2][r], acc[mi][3][r]));
      m = fmaxf(m, __shfl_xor(m, 1));
      m = fmaxf(m, __shfl_xor(m, 2));
      m = fmaxf(m, __shfl_xor(m, 4));
      m = fmaxf(m, __shfl_xor(m, 8));
      if (lr == 0) wred[(w << 6) + (mi << 4) + (lg << 2) + r] = m;
    }
  __syncthreads();
  if (tid < 64)
    rowstat[tid] = fmaxf(fmaxf(wred[tid], wred[64 + tid]),
                         fmaxf(wred[128 + tid], wred[192 + tid]));
  __syncthreads();

  // exp + per-row sum
#pragma unroll
  for (int mi = 0; mi < 4; ++mi)
#pragma unroll
    for (int r = 0; r < 4; ++r) {
      const int row = (mi << 4) + (lg << 2) + r;
      const float m = rowstat[row];
      float s = 0.f;
#pragma unroll
      for (int ni = 0; ni < 4; ++ni) {
        float e = __expf(acc[mi][ni][r] - m);
        acc[mi][ni][r] = e;
        s += e;
      }
      s += __shfl_xor(s, 1);
      s += __shfl_xor(s, 2);
      s += __shfl_xor(s, 4);
      s += __shfl_xor(s, 8);
      if (lr == 0) wred[(w << 6) + row] = s;
    }
  __syncthreads();
  if (tid < 64)
    rowstat[tid] = 1.0f / (wred[tid] + wred[64 + tid] +
                           wred[128 + tid] + wred[192 + tid]);
  __syncthreads();

  // normalize + store (16 lanes = 64B dense segments)
#pragma unroll
  for (int mi = 0; mi < 4; ++mi)
#pragma unroll
    for (int r = 0; r < 4; ++r) {
      const int row = (mi << 4) + (lg << 2) + r;
      const float rinv = rowstat[row];
      float* orow = out + (size_t)(m0 + row) * KOUT + (w << 6) + lr;
#pragma unroll
      for (int ni = 0; ni < 4; ++ni)
        orow[ni << 4] = acc[mi][ni][r] * rinv;
    }
}

extern "C" void kernel_launch(void* const* d_in, const int* in_sizes, int n_in,
                              void* d_out, int out_size, void* d_ws, size_t ws_size,
                              hipStream_t stream) {
  (void)in_sizes; (void)n_in; (void)out_size; (void)ws_size;
  const float* x   = (const float*)d_in[0];
  const float* y   = (const float*)d_in[1];
  const float* Wch = (const float*)d_in[2];
  const float* bch = (const float*)d_in[3];
  const float* Wy  = (const float*)d_in[4];
  float* out = (float*)d_out;
  unsigned short* wbf = (unsigned short*)d_ws;                 // 512 KB
  float* biasws = (float*)((char*)d_ws + 512 * 1024);          // 64 KB

  hipLaunchKernelGGL(prep_kernel, dim3(320), dim3(256), 0, stream,
                     Wch, y, Wy, bch, wbf, biasws);
  hipLaunchKernelGGL(fused_kernel, dim3(1024), dim3(256), 0, stream,
                     x, wbf, biasws, out);
}